// Round 8
// baseline (142.606 us; speedup 1.0000x reference)
//
#include <hip/hip_runtime.h>

typedef float f32x4 __attribute__((ext_vector_type(4)));
typedef __bf16 bf16x8 __attribute__((ext_vector_type(8)));

__device__ __forceinline__ unsigned short f2bf(float f) {
  unsigned u = __builtin_bit_cast(unsigned, f);
  u = (u + 0x7FFFu + ((u >> 16) & 1u)) >> 16;
  return (unsigned short)u;
}

__device__ __forceinline__ f32x4 MFMA16(uint4 a, uint4 b, f32x4 c) {
  return __builtin_amdgcn_mfma_f32_16x16x32_bf16(
      __builtin_bit_cast(bf16x8, a), __builtin_bit_cast(bf16x8, b), c, 0, 0, 0);
}

// ---------------- weight prep ----------------
// wd image:   [8 kc][128 o][40 (32 valid + 8 pad)] = 40960 elems (stage-1 LDS staging)
// wrs2 image: [3 p][4 kk][128 o][32 kl] unpadded   = 49152 elems (stage-2 global reads)
__global__ void wn_prep(const float* __restrict__ wd, const float* __restrict__ wres,
                        const float* __restrict__ wskip, unsigned short* __restrict__ ws16) {
  int g = blockIdx.x * 256 + threadIdx.x;   // grid 352*256 = 90112 exactly
  if (g < 40960) {
    int kc = g / 5120, rem = g - kc * 5120;
    int o = rem / 40, c = rem - o * 40;
    float v = 0.f;
    if (c < 32) {
      int k = kc * 32 + c;
      int tap = k >> 7, i = k & 127;
      v = wd[(o << 8) + (i << 1) + tap];   // w_dil[o][i][tap], shape (128,128,2)
    }
    ws16[g] = f2bf(v);
  } else {
    int g2 = g - 40960;  // < 49152
    int pkk = g2 >> 12;           // 0..11
    int rem = g2 & 4095;
    int o = rem >> 5, kl = rem & 31;
    int p = pkk >> 2, kk = pkk & 3;
    int k = kk * 32 + kl;
    float v = (p == 0) ? wres[o * 128 + k] : wskip[((p - 1) * 128 + o) * 128 + k];
    ws16[40960 + g2] = f2bf(v);
  }
}

// ---------------- fused main kernel ----------------
// 256 threads (4 waves, 2Mx2N), T-tile 64. LDS shorts:
//   xls @0: [2][64][40] (5120) ; wls @5120: [2][128][40] (10240)
//   actT[64][140] (8960) @0 — aliases xls+wls (both dead after stage 1)
// total 15360 sh = 30720 B -> 5 blocks/CU; __launch_bounds__(256,5) -> 20 waves/CU.
__global__ __launch_bounds__(256, 5) void wn_main(
    const float* __restrict__ x,
    const float* __restrict__ bres_g,
    const float* __restrict__ bskip_g,
    const unsigned short* __restrict__ wd_img,
    const unsigned short* __restrict__ wrs2_img,
    float* __restrict__ out,
    float* __restrict__ skipo) {
  extern __shared__ unsigned short lds[];
  unsigned short* xls  = lds;          // [2][64][40]
  unsigned short* wls  = lds + 5120;   // [2][128][40]
  unsigned short* actT = lds;          // [64][140], aliases staging (sequenced)

  // XCD swizzle: b = w&7 -> one batch per XCD; heavy 3-pass tiles first.
  const int w = blockIdx.x;            // 0..1983
  const int b = w & 7;
  const int tile = 247 - (w >> 3);     // 247..0 (heavy first)
  const int t0 = tile * 64;

  const int tid = threadIdx.x;
  const int lane = tid & 63;
  const int wv = tid >> 6;
  const int mw = wv >> 1;     // 0..1 -> M offset mw*64
  const int nw = wv & 1;      // 0..1 -> N offset nw*32
  const int l15 = lane & 15;
  const int lhi = lane >> 4;

  // staging mapping: k-major lanes
  const int kq = tid & 7;     // k-group of 4
  const int tpr = tid >> 3;   // 0..31 -> t pair

  const float* xb_base = x + (size_t)b * (128 * 16384);

  float2 xr[4];
  uint4 wrA, wrB, wrC;

  auto issueX = [&](int kc) {
    int kglob = kc * 32 + kq * 4;
    int tap = kglob >> 7;
    int ib = kglob & 127;
    const float* p = xb_base + (size_t)ib * 16384 + (t0 + tap * 512 + tpr * 2);
    xr[0] = *(const float2*)(p);
    xr[1] = *(const float2*)(p + 16384);
    xr[2] = *(const float2*)(p + 32768);
    xr[3] = *(const float2*)(p + 49152);
  };
  auto writeX = [&](int buf) {
    unsigned short* dst = xls + buf * 2560;
    int r0 = tpr * 2;
    ushort4 a0, a1;
    a0.x = f2bf(xr[0].x); a0.y = f2bf(xr[1].x); a0.z = f2bf(xr[2].x); a0.w = f2bf(xr[3].x);
    a1.x = f2bf(xr[0].y); a1.y = f2bf(xr[1].y); a1.z = f2bf(xr[2].y); a1.w = f2bf(xr[3].y);
    *(ushort4*)(dst + r0 * 40 + kq * 4) = a0;
    *(ushort4*)(dst + (r0 + 1) * 40 + kq * 4) = a1;
  };
  auto loadW1 = [&](int kc) {   // wd chunk: 5120 sh = 640 uint4, 256 threads
    const uint4* src = (const uint4*)(wd_img + kc * 5120);
    wrA = src[tid];
    wrB = src[tid + 256];
    if (tid < 128) wrC = src[tid + 512];
  };
  auto writeW1 = [&](int buf) {
    uint4* dst = (uint4*)(wls + buf * 5120);
    dst[tid] = wrA;
    dst[tid + 256] = wrB;
    if (tid < 128) dst[tid + 512] = wrC;
  };

  f32x4 acc[4][2];
#pragma unroll
  for (int i = 0; i < 4; ++i)
#pragma unroll
    for (int j = 0; j < 2; ++j) acc[i][j] = (f32x4){0.f, 0.f, 0.f, 0.f};

  // ---- stage 1: pre = [W0|W1] @ [x(t); x(t+512)], K=256 in 8 chunks ----
  issueX(0); loadW1(0);
  writeX(0); writeW1(0);
  __syncthreads();

#pragma unroll
  for (int kc = 0; kc < 8; ++kc) {
    const int buf = kc & 1;
    if (kc < 7) { issueX(kc + 1); loadW1(kc + 1); }
    const unsigned short* wbuf = wls + buf * 5120;
    const unsigned short* xbuf = xls + buf * 2560;
    uint4 af[4], bfr[2];
#pragma unroll
    for (int mi = 0; mi < 4; ++mi)
      af[mi] = *(const uint4*)(wbuf + (mw * 64 + mi * 16 + l15) * 40 + lhi * 8);
#pragma unroll
    for (int ni = 0; ni < 2; ++ni)
      bfr[ni] = *(const uint4*)(xbuf + (nw * 32 + ni * 16 + l15) * 40 + lhi * 8);
#pragma unroll
    for (int mi = 0; mi < 4; ++mi)
#pragma unroll
      for (int ni = 0; ni < 2; ++ni)
        acc[mi][ni] = MFMA16(af[mi], bfr[ni], acc[mi][ni]);
    if (kc < 7) { writeX(buf ^ 1); writeW1(buf ^ 1); }
    __syncthreads();
  }

  // ---- activation -> actT[t][o] (aliases staging; ordered by last sync) ----
#pragma unroll
  for (int mi = 0; mi < 4; ++mi) {
#pragma unroll
    for (int ni = 0; ni < 2; ++ni) {
      ushort4 av;
#pragma unroll
      for (int r = 0; r < 4; ++r) {
        float p = acc[mi][ni][r];
        p = fminf(fmaxf(p, -15.f), 15.f);
        float ep = __expf(p);
        float e2 = ep * ep;
        float sg = ep * __builtin_amdgcn_rcpf(1.f + ep);
        float th = (e2 - 1.f) * __builtin_amdgcn_rcpf(e2 + 1.f);
        ((unsigned short*)&av)[r] = f2bf(th * sg);
      }
      int trow = nw * 32 + ni * 16 + l15;
      int o0 = mw * 64 + mi * 16 + lhi * 4;
      *(ushort4*)(actT + trow * 140 + o0) = av;
    }
  }
  __syncthreads();   // actT handoff; stage 2 is barrier-free

  // ---- stage 2: out (pass 0) and skip (passes 1,2); weights from L2-hot global ----
  const int npass = (tile >= 184) ? 3 : 1;
  for (int p = 0; p < npass; ++p) {
    f32x4 acc2[4][2];
#pragma unroll
    for (int i = 0; i < 4; ++i)
#pragma unroll
      for (int j = 0; j < 2; ++j) acc2[i][j] = (f32x4){0.f, 0.f, 0.f, 0.f};

#pragma unroll
    for (int kk = 0; kk < 4; ++kk) {
      uint4 af[4], bfr[2];
      const unsigned short* wbase = wrs2_img + ((p * 4 + kk) << 12) + lhi * 8;
#pragma unroll
      for (int mi = 0; mi < 4; ++mi)
        af[mi] = *(const uint4*)(wbase + (mw * 64 + mi * 16 + l15) * 32);
#pragma unroll
      for (int ni = 0; ni < 2; ++ni)
        bfr[ni] = *(const uint4*)(actT + (nw * 32 + ni * 16 + l15) * 140 + kk * 32 + lhi * 8);
#pragma unroll
      for (int mi = 0; mi < 4; ++mi)
#pragma unroll
        for (int ni = 0; ni < 2; ++ni)
          acc2[mi][ni] = MFMA16(af[mi], bfr[ni], acc2[mi][ni]);
    }

    if (p == 0) {
#pragma unroll
      for (int mi = 0; mi < 4; ++mi) {
        int o0 = mw * 64 + mi * 16 + lhi * 4;
        float br[4];
#pragma unroll
        for (int r = 0; r < 4; ++r) br[r] = bres_g[o0 + r];
#pragma unroll
        for (int ni = 0; ni < 2; ++ni) {
          int tl = nw * 32 + ni * 16 + l15;
#pragma unroll
          for (int r = 0; r < 4; ++r) {
            size_t row = (size_t)(b * 128 + o0 + r);
            float v = acc2[mi][ni][r] + br[r] + x[row * 16384 + 512 + t0 + tl];
            out[row * 15872 + t0 + tl] = v;
          }
        }
      }
    } else {
#pragma unroll
      for (int mi = 0; mi < 4; ++mi) {
        int o2 = (p - 1) * 128 + mw * 64 + mi * 16 + lhi * 4;
        float bs[4];
#pragma unroll
        for (int r = 0; r < 4; ++r) bs[r] = bskip_g[o2 + r];
#pragma unroll
        for (int ni = 0; ni < 2; ++ni) {
          int tl = nw * 32 + ni * 16 + l15;
          int s = t0 + tl - 11776;
#pragma unroll
          for (int r = 0; r < 4; ++r) {
            skipo[(size_t)(b * 256 + o2 + r) * 4096 + s] = acc2[mi][ni][r] + bs[r];
          }
        }
      }
    }
  }
}

extern "C" void kernel_launch(void* const* d_in, const int* in_sizes, int n_in,
                              void* d_out, int out_size, void* d_ws, size_t ws_size,
                              hipStream_t stream) {
  const float* x      = (const float*)d_in[0];
  const float* w_dil  = (const float*)d_in[1];
  const float* w_res  = (const float*)d_in[2];
  const float* b_res  = (const float*)d_in[3];
  const float* w_skip = (const float*)d_in[4];
  const float* b_skip = (const float*)d_in[5];
  unsigned short* ws16 = (unsigned short*)d_ws;
  float* out = (float*)d_out;
  float* skipo = out + 16252928;  // 8*128*15872

  wn_prep<<<352, 256, 0, stream>>>(w_dil, w_res, w_skip, ws16);

  wn_main<<<1984, 256, 30720, stream>>>(x, b_res, b_skip, ws16, ws16 + 40960, out, skipo);
}

// Round 9
// 89.345 us; speedup vs baseline: 1.5961x; 1.5961x over previous
//
#include <hip/hip_runtime.h>

typedef float f32x4 __attribute__((ext_vector_type(4)));
typedef __bf16 bf16x8 __attribute__((ext_vector_type(8)));

__device__ __forceinline__ unsigned short f2bf(float f) {
  unsigned u = __builtin_bit_cast(unsigned, f);
  u = (u + 0x7FFFu + ((u >> 16) & 1u)) >> 16;
  return (unsigned short)u;
}

__device__ __forceinline__ f32x4 MFMA16(uint4 a, uint4 b, f32x4 c) {
  return __builtin_amdgcn_mfma_f32_16x16x32_bf16(
      __builtin_bit_cast(bf16x8, a), __builtin_bit_cast(bf16x8, b), c, 0, 0, 0);
}

// ---------------- weight prep: unpadded bf16 images ----------------
// wd2:  [8 kc][128 o][32 kl]      = 32768 elems (64B rows -> clean granules)
// wrs2: [3 p][4 kk][128 o][32 kl] = 49152 elems
__global__ void wn_prep(const float* __restrict__ wd, const float* __restrict__ wres,
                        const float* __restrict__ wskip, unsigned short* __restrict__ ws16) {
  int g = blockIdx.x * 256 + threadIdx.x;   // grid 320*256 = 81920 exactly
  if (g < 32768) {
    int kc = g >> 12, rem = g & 4095;
    int o = rem >> 5, kl = rem & 31;
    int k = kc * 32 + kl;
    int tap = k >> 7, i = k & 127;
    ws16[g] = f2bf(wd[(o << 8) + (i << 1) + tap]);  // w_dil (128,128,2)
  } else {
    int g2 = g - 32768;
    int pkk = g2 >> 12;           // 0..11
    int rem = g2 & 4095;
    int o = rem >> 5, kl = rem & 31;
    int p = pkk >> 2, kk = pkk & 3;
    int k = kk * 32 + kl;
    float v = (p == 0) ? wres[o * 128 + k] : wskip[((p - 1) * 128 + o) * 128 + k];
    ws16[32768 + g2] = f2bf(v);
  }
}

// ---------------- fused main kernel ----------------
// 256 threads (4 waves, 2Mx2N), T-tile 64. LDS shorts:
//   xls @0: [2][64][40] (5120 sh); actT[64][140] (8960 sh) @0 aliases xls
//   (alias sequenced by the stage-1 closing barrier). Total 8960 sh = 17920 B
//   -> 8 blocks/CU LDS-wise; VGPR (~80-100) gives ~5-6 blocks. ~2x R6's TLP.
// Weights (stage 1 AND 2) direct from L2-hot unpadded global images.
__global__ __launch_bounds__(256, 4) void wn_main(
    const float* __restrict__ x,
    const float* __restrict__ bres_g,
    const float* __restrict__ bskip_g,
    const unsigned short* __restrict__ wd2_img,
    const unsigned short* __restrict__ wrs2_img,
    float* __restrict__ out,
    float* __restrict__ skipo) {
  extern __shared__ unsigned short lds[];
  unsigned short* xls  = lds;          // [2][64][40]
  unsigned short* actT = lds;          // [64][140], aliases xls (sequenced)

  // XCD swizzle: b = w&7 -> one batch per XCD; heavy 3-pass tiles first.
  const int w = blockIdx.x;            // 0..1983
  const int b = w & 7;
  const int tile = 247 - (w >> 3);     // 247..0 (heavy first)
  const int t0 = tile * 64;

  const int tid = threadIdx.x;
  const int lane = tid & 63;
  const int wv = tid >> 6;
  const int mw = wv >> 1;     // 0..1 -> M offset mw*64
  const int nw = wv & 1;      // 0..1 -> N offset nw*32
  const int l15 = lane & 15;
  const int lhi = lane >> 4;

  // staging mapping: k-major lanes
  const int kq = tid & 7;     // k-group of 4
  const int tpr = tid >> 3;   // 0..31 -> t pair

  const float* xb_base = x + (size_t)b * (128 * 16384);

  float2 xr[4];

  auto issueX = [&](int kc) {
    int kglob = kc * 32 + kq * 4;
    int tap = kglob >> 7;
    int ib = kglob & 127;
    const float* p = xb_base + (size_t)ib * 16384 + (t0 + tap * 512 + tpr * 2);
    xr[0] = *(const float2*)(p);
    xr[1] = *(const float2*)(p + 16384);
    xr[2] = *(const float2*)(p + 32768);
    xr[3] = *(const float2*)(p + 49152);
  };
  auto writeX = [&](int buf) {
    unsigned short* dst = xls + buf * 2560;
    int r0 = tpr * 2;
    ushort4 a0, a1;
    a0.x = f2bf(xr[0].x); a0.y = f2bf(xr[1].x); a0.z = f2bf(xr[2].x); a0.w = f2bf(xr[3].x);
    a1.x = f2bf(xr[0].y); a1.y = f2bf(xr[1].y); a1.z = f2bf(xr[2].y); a1.w = f2bf(xr[3].y);
    *(ushort4*)(dst + r0 * 40 + kq * 4) = a0;
    *(ushort4*)(dst + (r0 + 1) * 40 + kq * 4) = a1;
  };

  f32x4 acc[4][2];
#pragma unroll
  for (int i = 0; i < 4; ++i)
#pragma unroll
    for (int j = 0; j < 2; ++j) acc[i][j] = (f32x4){0.f, 0.f, 0.f, 0.f};

  // ---- stage 1: pre = [W0|W1] @ [x(t); x(t+512)], K=256 in 8 chunks ----
  issueX(0);
  writeX(0);
  __syncthreads();

#pragma unroll 1
  for (int kc = 0; kc < 8; ++kc) {
    const int buf = kc & 1;
    if (kc < 7) issueX(kc + 1);          // depth-1 x prefetch (R6 mechanics)
    // A-frags direct from unpadded L2-hot image (pure reads, no barrier dep)
    uint4 af[4];
    const unsigned short* wbase = wd2_img + (kc << 12) + lhi * 8;
#pragma unroll
    for (int mi = 0; mi < 4; ++mi)
      af[mi] = *(const uint4*)(wbase + (mw * 64 + mi * 16 + l15) * 32);
    uint4 bfr[2];
    const unsigned short* xbuf = xls + buf * 2560;
#pragma unroll
    for (int ni = 0; ni < 2; ++ni)
      bfr[ni] = *(const uint4*)(xbuf + (nw * 32 + ni * 16 + l15) * 40 + lhi * 8);
#pragma unroll
    for (int mi = 0; mi < 4; ++mi)
#pragma unroll
      for (int ni = 0; ni < 2; ++ni)
        acc[mi][ni] = MFMA16(af[mi], bfr[ni], acc[mi][ni]);
    if (kc < 7) writeX(buf ^ 1);
    __syncthreads();
  }

  // ---- activation -> actT[t][o] (aliases xls; ordered by closing barrier) ----
#pragma unroll
  for (int mi = 0; mi < 4; ++mi) {
#pragma unroll
    for (int ni = 0; ni < 2; ++ni) {
      ushort4 av;
#pragma unroll
      for (int r = 0; r < 4; ++r) {
        float p = acc[mi][ni][r];
        p = fminf(fmaxf(p, -15.f), 15.f);
        float ep = __expf(p);
        float e2 = ep * ep;
        float sg = ep * __builtin_amdgcn_rcpf(1.f + ep);
        float th = (e2 - 1.f) * __builtin_amdgcn_rcpf(e2 + 1.f);
        ((unsigned short*)&av)[r] = f2bf(th * sg);
      }
      int trow = nw * 32 + ni * 16 + l15;
      int o0 = mw * 64 + mi * 16 + lhi * 4;
      *(ushort4*)(actT + trow * 140 + o0) = av;
    }
  }
  __syncthreads();   // actT handoff; stage 2 is barrier-free

  // ---- stage 2: out (pass 0) and skip (passes 1,2); weights direct ----
  const int npass = (tile >= 184) ? 3 : 1;
#pragma unroll 1
  for (int p = 0; p < npass; ++p) {
    f32x4 acc2[4][2];
#pragma unroll
    for (int i = 0; i < 4; ++i)
#pragma unroll
      for (int j = 0; j < 2; ++j) acc2[i][j] = (f32x4){0.f, 0.f, 0.f, 0.f};

#pragma unroll 1
    for (int kk = 0; kk < 4; ++kk) {
      uint4 af[4], bfr[2];
      const unsigned short* wbase = wrs2_img + ((p * 4 + kk) << 12) + lhi * 8;
#pragma unroll
      for (int mi = 0; mi < 4; ++mi)
        af[mi] = *(const uint4*)(wbase + (mw * 64 + mi * 16 + l15) * 32);
#pragma unroll
      for (int ni = 0; ni < 2; ++ni)
        bfr[ni] = *(const uint4*)(actT + (nw * 32 + ni * 16 + l15) * 140 + kk * 32 + lhi * 8);
#pragma unroll
      for (int mi = 0; mi < 4; ++mi)
#pragma unroll
        for (int ni = 0; ni < 2; ++ni)
          acc2[mi][ni] = MFMA16(af[mi], bfr[ni], acc2[mi][ni]);
    }

    if (p == 0) {
#pragma unroll
      for (int mi = 0; mi < 4; ++mi) {
        int o0 = mw * 64 + mi * 16 + lhi * 4;
        float br[4];
#pragma unroll
        for (int r = 0; r < 4; ++r) br[r] = bres_g[o0 + r];
#pragma unroll
        for (int ni = 0; ni < 2; ++ni) {
          int tl = nw * 32 + ni * 16 + l15;
#pragma unroll
          for (int r = 0; r < 4; ++r) {
            size_t row = (size_t)(b * 128 + o0 + r);
            float v = acc2[mi][ni][r] + br[r] + x[row * 16384 + 512 + t0 + tl];
            out[row * 15872 + t0 + tl] = v;
          }
        }
      }
    } else {
#pragma unroll
      for (int mi = 0; mi < 4; ++mi) {
        int o2 = (p - 1) * 128 + mw * 64 + mi * 16 + lhi * 4;
        float bs[4];
#pragma unroll
        for (int r = 0; r < 4; ++r) bs[r] = bskip_g[o2 + r];
#pragma unroll
        for (int ni = 0; ni < 2; ++ni) {
          int tl = nw * 32 + ni * 16 + l15;
          int s = t0 + tl - 11776;
#pragma unroll
          for (int r = 0; r < 4; ++r) {
            skipo[(size_t)(b * 256 + o2 + r) * 4096 + s] = acc2[mi][ni][r] + bs[r];
          }
        }
      }
    }
  }
}

extern "C" void kernel_launch(void* const* d_in, const int* in_sizes, int n_in,
                              void* d_out, int out_size, void* d_ws, size_t ws_size,
                              hipStream_t stream) {
  const float* x      = (const float*)d_in[0];
  const float* w_dil  = (const float*)d_in[1];
  const float* w_res  = (const float*)d_in[2];
  const float* b_res  = (const float*)d_in[3];
  const float* w_skip = (const float*)d_in[4];
  const float* b_skip = (const float*)d_in[5];
  unsigned short* ws16 = (unsigned short*)d_ws;
  float* out = (float*)d_out;
  float* skipo = out + 16252928;  // 8*128*15872

  wn_prep<<<320, 256, 0, stream>>>(w_dil, w_res, w_skip, ws16);

  wn_main<<<1984, 256, 17920, stream>>>(x, b_res, b_skip, ws16, ws16 + 32768, out, skipo);
}